// Round 12
// baseline (424.395 us; speedup 1.0000x reference)
//
#include <hip/hip_runtime.h>
#include <hip/hip_bf16.h>
#include <math.h>

static constexpr int N = 50000;
static constexpr int E = 800000;
static constexpr int F = 128;
static constexpr int H = 64;
static constexpr int G = 512;
static constexpr int C = 10;
static constexpr int CAP = 256;    // per-graph capacity for 24-bit-tied edges (~1-3 expected)
static constexpr int NFB = (E / 4 + 255) / 256;   // 782 fill blocks (int4-granular, guarded)
static constexpr int GB1 = N / 16;        // 3125 layer-1 gemm blocks (16 rows)
static constexpr int GB2 = (N + 31) / 32; // 1563 layer-2 gemm blocks (32 rows, guarded)
static constexpr int SB = E / 256;        // 3125 score blocks

static inline int cdiv(long a, int b) { return (int)((a + b - 1) / b); }

__device__ __forceinline__ float uinv_score(unsigned u) {
  // inverse of the order-preserving float->uint map
  return (u & 0x80000000u) ? __uint_as_float(u & 0x7fffffffu) : __uint_as_float(~u);
}

// ---- packed slot record: 63 bits in int2 ----
// a = src(17) | dst_lo15(15)<<17 ; b = dst_hi2(2) | g(9)<<2 | eid(20)<<11
__device__ __forceinline__ int2 pack_slot(int s, int d, int g, int e) {
  unsigned a = (unsigned)s | ((unsigned)(d & 0x7FFF) << 17);
  unsigned b = ((unsigned)d >> 15) | ((unsigned)g << 2) | ((unsigned)e << 11);
  return make_int2((int)a, (int)b);
}
__device__ __forceinline__ int slot_src(int2 p) { return p.x & 0x1FFFF; }
__device__ __forceinline__ int slot_dst(int2 p) {
  return (int)(((unsigned)p.x >> 17) | (((unsigned)p.y & 3u) << 15));
}
__device__ __forceinline__ int slot_g(int2 p) { return (int)(((unsigned)p.y >> 2) & 0x1FFu); }
__device__ __forceinline__ int slot_eid(int2 p) { return (int)((unsigned)p.y >> 11); }

// ---- deg (in-deg over dst, int4 x4-ILP atomics) + goff boundaries + RANKS.
// The atomicAdd RETURN VALUE is each edge's rank within its dst node — stored
// to rank16[e] (coalesced ushort4). This lets the fill pass compute its slot
// as off[d]+rank with NO atomics.
__global__ void k_deg_goff(const int* __restrict__ dst, const int* __restrict__ batch,
                           int* __restrict__ deg, int* __restrict__ goff,
                           unsigned short* __restrict__ rank16) {
  int tid = threadIdx.x;
  for (int i = blockIdx.x * 256 + tid; i < N; i += gridDim.x * 256) {
    int b = batch[i];
    if (i == 0) {
      for (int g = 0; g <= b; ++g) goff[g] = 0;
    } else {
      int p = batch[i - 1];
      for (int g = p + 1; g <= b; ++g) goff[g] = i;
    }
    if (i == N - 1) {
      for (int g = b + 1; g <= G; ++g) goff[g] = N;
    }
  }
  const int4* d4 = (const int4*)dst;
  for (int i = blockIdx.x * 256 + tid; i < E / 4; i += gridDim.x * 256) {
    int4 v = d4[i];
    ushort4 rk;
    rk.x = (unsigned short)atomicAdd(&deg[v.x], 1);
    rk.y = (unsigned short)atomicAdd(&deg[v.y], 1);
    rk.z = (unsigned short)atomicAdd(&deg[v.z], 1);
    rk.w = (unsigned short)atomicAdd(&deg[v.w], 1);
    *(ushort4*)(rank16 + (size_t)i * 4) = rk;
  }
}

// ---- parallel exclusive scan, 2 kernels (block-sum scan folded into pass c) ----
__global__ void k_scan_a(const int* __restrict__ cnt, int* __restrict__ off,
                         int* __restrict__ bsum, int n) {
  __shared__ int wsum[16];
  int tid = threadIdx.x, lane = tid & 63, wv = tid >> 6;
  int idx = blockIdx.x * 4096 + tid * 4;
  int v0 = (idx + 0 < n) ? cnt[idx + 0] : 0;
  int v1 = (idx + 1 < n) ? cnt[idx + 1] : 0;
  int v2 = (idx + 2 < n) ? cnt[idx + 2] : 0;
  int v3 = (idx + 3 < n) ? cnt[idx + 3] : 0;
  int local = v0 + v1 + v2 + v3;
  int inc = local;
  for (int d = 1; d < 64; d <<= 1) {
    int t = __shfl_up(inc, d);
    if (lane >= d) inc += t;
  }
  if (lane == 63) wsum[wv] = inc;
  __syncthreads();
  if (tid < 16) {
    int t = wsum[tid];
    for (int d = 1; d < 16; d <<= 1) {
      int u = __shfl_up(t, d);
      if (tid >= d) t += u;
    }
    wsum[tid] = t;
  }
  __syncthreads();
  int woff = (wv > 0) ? wsum[wv - 1] : 0;
  int excl = woff + inc - local;
  if (idx + 0 < n) off[idx + 0] = excl;
  if (idx + 1 < n) off[idx + 1] = excl + v0;
  if (idx + 2 < n) off[idx + 2] = excl + v0 + v1;
  if (idx + 3 < n) off[idx + 3] = excl + v0 + v1 + v2;
  if (tid == 0) bsum[blockIdx.x] = wsum[15];
}

// adds block-sum prefix; every block redundantly scans the <=32 block sums (cheap)
__global__ void k_scan_c(int* __restrict__ off, const int* __restrict__ bsum, int n, int nb) {
  __shared__ int spre[34];
  int tid = threadIdx.x;
  if (tid < 32) {
    int v = (tid < nb) ? bsum[tid] : 0;
    int inc = v;
    for (int d = 1; d < 32; d <<= 1) {
      int t = __shfl_up(inc, d);
      if (tid >= d) inc += t;
    }
    spre[tid] = inc - v;   // exclusive; spre[nb] = total
  }
  __syncthreads();
  int i = blockIdx.x * 256 + tid;
  if (i < n) {
    off[i] = off[i] + spre[i >> 12];
  } else if (i == n) {
    off[n] = spre[nb];
  }
}

// ---- FUSED: atomic-free rank-based fill + layer-1 dense GEMM, 1:4 interleave.
// blockIdx%5==0 -> fill role: slot = off[dst] + rank16[e] (no RMW, single
// linear int4 pass; scatter csrp 8B + coalesced einv int4).
// else -> gemm role (y=x@W1l, r=x@W1r+b, 16 rows) hiding in fill's shadow.
__global__ void k_fill_gemm(const int* __restrict__ src, const int* __restrict__ dst,
                            const unsigned short* __restrict__ rank16,
                            const int* __restrict__ batch, const int* __restrict__ off,
                            int2* __restrict__ csrp, int* __restrict__ einv,
                            const float* __restrict__ x, const float* __restrict__ Wl,
                            const float* __restrict__ Wr, const float* __restrict__ bl,
                            float* __restrict__ y, float* __restrict__ r) {
  __shared__ float sx[16][F];
  int lane = threadIdx.x, ty = threadIdx.y;
  int tid = ty * 64 + lane;
  int bq = blockIdx.x / 5, br = blockIdx.x - bq * 5;
  if (br == 0) {
    // ---- fill role: int4 index i covers edges [4i, 4i+4) ----
    int i = bq * 256 + tid;
    if (i < E / 4) {
      int4 dv = ((const int4*)dst)[i];
      int4 sv = ((const int4*)src)[i];
      ushort4 rv = *(const ushort4*)(rank16 + (size_t)i * 4);
      int dd[4] = {dv.x, dv.y, dv.z, dv.w};
      int ss[4] = {sv.x, sv.y, sv.z, sv.w};
      int rr[4] = {rv.x, rv.y, rv.z, rv.w};
      int e0 = i * 4;
      int slots[4];
#pragma unroll
      for (int j = 0; j < 4; ++j) {
        int g = batch[ss[j]];
        int slot = off[dd[j]] + rr[j];
        csrp[slot] = pack_slot(ss[j], dd[j], g, e0 + j);
        slots[j] = slot;
      }
      *(int4*)(einv + e0) = make_int4(slots[0], slots[1], slots[2], slots[3]);
    }
    return;
  }
  // ---- gemm role: rows [gid*16, gid*16+16) ----
  int gid = bq * 4 + (br - 1);
  if (gid >= GB1) return;
  int row0 = gid * 16;
  const float4* gsrc = (const float4*)(x + (size_t)row0 * F);
  float4* sdst = (float4*)(&sx[0][0]);
#pragma unroll
  for (int i = tid; i < 16 * F / 4; i += 256) sdst[i] = gsrc[i];
  __syncthreads();
  float al[4], ar[4];
  float bias = bl[lane];
#pragma unroll
  for (int j = 0; j < 4; ++j) { al[j] = 0.f; ar[j] = bias; }
#pragma unroll 4
  for (int f = 0; f < F; ++f) {
    float wl = Wl[f * H + lane];
    float wr = Wr[f * H + lane];
#pragma unroll
    for (int j = 0; j < 4; ++j) {
      float xv = sx[ty * 4 + j][f];
      al[j] += xv * wl;
      ar[j] += xv * wr;
    }
  }
#pragma unroll
  for (int j = 0; j < 4; ++j) {
    int row = row0 + ty * 4 + j;
    y[(size_t)row * H + lane] = al[j];
    r[(size_t)row * H + lane] = ar[j];
  }
}

// ---- layer-1 aggregation (fp32 rows): eighth-wave per edge ----
__global__ void k_agg1(const float* __restrict__ y, const float* __restrict__ r,
                       const int2* __restrict__ csrp, const int* __restrict__ off,
                       float* __restrict__ out) {
  int node = blockIdx.x * 8 + threadIdx.y;
  int lane = threadIdx.x;
  int q = lane >> 3, c = lane & 7;
  int s0 = off[node], s1 = off[node + 1];
  float4 a0 = make_float4(0.f, 0.f, 0.f, 0.f);
  float4 a1 = make_float4(0.f, 0.f, 0.f, 0.f);
  int i = s0 + q;
  for (; i + 8 < s1; i += 16) {
    int se0 = slot_src(csrp[i]);
    int se1 = slot_src(csrp[i + 8]);
    const float4* p0 = (const float4*)(y + (size_t)se0 * H);
    const float4* p1 = (const float4*)(y + (size_t)se1 * H);
    float4 u0 = p0[c], v0 = p0[c + 8];
    float4 u1 = p1[c], v1 = p1[c + 8];
    a0.x += u0.x + u1.x; a0.y += u0.y + u1.y; a0.z += u0.z + u1.z; a0.w += u0.w + u1.w;
    a1.x += v0.x + v1.x; a1.y += v0.y + v1.y; a1.z += v0.z + v1.z; a1.w += v0.w + v1.w;
  }
  for (; i < s1; i += 8) {
    int se = slot_src(csrp[i]);
    const float4* p = (const float4*)(y + (size_t)se * H);
    float4 u = p[c], v = p[c + 8];
    a0.x += u.x; a0.y += u.y; a0.z += u.z; a0.w += u.w;
    a1.x += v.x; a1.y += v.y; a1.z += v.z; a1.w += v.w;
  }
#pragma unroll
  for (int d = 8; d < 64; d <<= 1) {
    a0.x += __shfl_xor(a0.x, d); a0.y += __shfl_xor(a0.y, d);
    a0.z += __shfl_xor(a0.z, d); a0.w += __shfl_xor(a0.w, d);
    a1.x += __shfl_xor(a1.x, d); a1.y += __shfl_xor(a1.y, d);
    a1.z += __shfl_xor(a1.z, d); a1.w += __shfl_xor(a1.w, d);
  }
  if (q == 0) {
    float inv = 1.f / fmaxf((float)(s1 - s0), 1.f);
    const float4* rp = (const float4*)(r + (size_t)node * H);
    float4 r0 = rp[c], r1 = rp[c + 8];
    float4 o0, o1;
    o0.x = fmaxf(a0.x * inv + r0.x, 0.f); o0.y = fmaxf(a0.y * inv + r0.y, 0.f);
    o0.z = fmaxf(a0.z * inv + r0.z, 0.f); o0.w = fmaxf(a0.w * inv + r0.w, 0.f);
    o1.x = fmaxf(a1.x * inv + r1.x, 0.f); o1.y = fmaxf(a1.y * inv + r1.y, 0.f);
    o1.z = fmaxf(a1.z * inv + r1.z, 0.f); o1.w = fmaxf(a1.w * inv + r1.w, 0.f);
    float4* op = (float4*)(out + (size_t)node * H);
    op[c] = o0; op[c + 8] = o1;
  }
}

// ---- FUSED: layer-2 weighted aggregation + layer-3 projections.
// Aggregation identical to k_agg_w, but the finished h2 row goes to LDS
// instead of global memory; after a barrier the block's 512 threads compute
// one projection output each (8 nodes x 64 cols): ybh2=bf16(h2@W3l),
// rb2=h2@W3r+b3 — same sequential f-order as the standalone gemm2h, so
// results are bit-identical. Kills the gemm2h launch + h2's 26MB roundtrip.
__global__ void k_agg_w_p3(const __hip_bfloat16* __restrict__ y, const float* __restrict__ r,
                           const int2* __restrict__ csr2, const int* __restrict__ cnt2,
                           const int* __restrict__ off, const unsigned* __restrict__ scoreu,
                           const float* __restrict__ W3l, const float* __restrict__ W3r,
                           const float* __restrict__ b3,
                           __hip_bfloat16* __restrict__ ybh2, float* __restrict__ rb2) {
  __shared__ float sh[8][H];
  int node = blockIdx.x * 8 + threadIdx.y;
  int lane = threadIdx.x;
  int ty = threadIdx.y;
  int q = lane >> 3, c = lane & 7;
  int b0 = off[node], cn = cnt2[node];
  float a[8] = {0.f, 0.f, 0.f, 0.f, 0.f, 0.f, 0.f, 0.f};
  for (int j = q; j < cn; j += 8) {
    int2 sw = csr2[b0 + j];
    float w = __int_as_float(sw.y);
    uint4 pk = ((const uint4*)((const unsigned short*)y + (size_t)sw.x * H))[c];
    a[0] += w * __uint_as_float(pk.x << 16); a[1] += w * __uint_as_float(pk.x & 0xffff0000u);
    a[2] += w * __uint_as_float(pk.y << 16); a[3] += w * __uint_as_float(pk.y & 0xffff0000u);
    a[4] += w * __uint_as_float(pk.z << 16); a[5] += w * __uint_as_float(pk.z & 0xffff0000u);
    a[6] += w * __uint_as_float(pk.w << 16); a[7] += w * __uint_as_float(pk.w & 0xffff0000u);
  }
#pragma unroll
  for (int d = 8; d < 64; d <<= 1) {
#pragma unroll
    for (int j = 0; j < 8; ++j) a[j] += __shfl_xor(a[j], d);
  }
  if (q == 0) {
    int degn = off[node + 1] - off[node];
    float inv = 1.f / fmaxf((float)degn, 1.f);
    const float4* rp = (const float4*)(r + (size_t)node * H);
    float4 r0 = rp[2 * c], r1 = rp[2 * c + 1];
    sh[ty][8 * c + 0] = fmaxf(a[0] * inv + r0.x, 0.f);
    sh[ty][8 * c + 1] = fmaxf(a[1] * inv + r0.y, 0.f);
    sh[ty][8 * c + 2] = fmaxf(a[2] * inv + r0.z, 0.f);
    sh[ty][8 * c + 3] = fmaxf(a[3] * inv + r0.w, 0.f);
    sh[ty][8 * c + 4] = fmaxf(a[4] * inv + r1.x, 0.f);
    sh[ty][8 * c + 5] = fmaxf(a[5] * inv + r1.y, 0.f);
    sh[ty][8 * c + 6] = fmaxf(a[6] * inv + r1.z, 0.f);
    sh[ty][8 * c + 7] = fmaxf(a[7] * inv + r1.w, 0.f);
  }
  __syncthreads();
  // ---- layer-3 projection: thread (lane, ty) -> node ty, column `lane` ----
  float al = 0.f, ar = b3[lane];
#pragma unroll 4
  for (int f = 0; f < H; ++f) {
    float v = sh[ty][f];
    al += v * W3l[f * H + lane];
    ar += v * W3r[f * H + lane];
  }
  ybh2[(size_t)node * H + lane] = __float2bfloat16(al);
  rb2[(size_t)node * H + lane] = ar;
}

// ---- weighted aggregation over COMPACTED edges (bf16 rows): eighth-wave ----
__global__ void k_agg_w(const __hip_bfloat16* __restrict__ y, const float* __restrict__ r,
                        const int2* __restrict__ csr2, const int* __restrict__ cnt2,
                        const int* __restrict__ off, float* __restrict__ out) {
  int node = blockIdx.x * 8 + threadIdx.y;
  int lane = threadIdx.x;
  int q = lane >> 3, c = lane & 7;
  int b0 = off[node], cn = cnt2[node];
  float a[8] = {0.f, 0.f, 0.f, 0.f, 0.f, 0.f, 0.f, 0.f};
  for (int j = q; j < cn; j += 8) {
    int2 sw = csr2[b0 + j];
    float w = __int_as_float(sw.y);
    uint4 pk = ((const uint4*)((const unsigned short*)y + (size_t)sw.x * H))[c];
    a[0] += w * __uint_as_float(pk.x << 16); a[1] += w * __uint_as_float(pk.x & 0xffff0000u);
    a[2] += w * __uint_as_float(pk.y << 16); a[3] += w * __uint_as_float(pk.y & 0xffff0000u);
    a[4] += w * __uint_as_float(pk.z << 16); a[5] += w * __uint_as_float(pk.z & 0xffff0000u);
    a[6] += w * __uint_as_float(pk.w << 16); a[7] += w * __uint_as_float(pk.w & 0xffff0000u);
  }
#pragma unroll
  for (int d = 8; d < 64; d <<= 1) {
#pragma unroll
    for (int j = 0; j < 8; ++j) a[j] += __shfl_xor(a[j], d);
  }
  if (q == 0) {
    int degn = off[node + 1] - off[node];
    float inv = 1.f / fmaxf((float)degn, 1.f);
    const float4* rp = (const float4*)(r + (size_t)node * H);
    float4 r0 = rp[2 * c], r1 = rp[2 * c + 1];
    float4 o0, o1;
    o0.x = fmaxf(a[0] * inv + r0.x, 0.f); o0.y = fmaxf(a[1] * inv + r0.y, 0.f);
    o0.z = fmaxf(a[2] * inv + r0.z, 0.f); o0.w = fmaxf(a[3] * inv + r0.w, 0.f);
    o1.x = fmaxf(a[4] * inv + r1.x, 0.f); o1.y = fmaxf(a[5] * inv + r1.y, 0.f);
    o1.z = fmaxf(a[6] * inv + r1.z, 0.f); o1.w = fmaxf(a[7] * inv + r1.w, 0.f);
    float4* op = (float4*)(out + (size_t)node * H);
    op[2 * c] = o0; op[2 * c + 1] = o1;
  }
}

// ---- FUSED: edge-slot-parallel scoring + layer-2 bf16 GEMM, interleaved 2:1.
// blockIdx%3==0 -> gemm2h role (32 rows of h1@W2l / h1@W2r+b2l, guarded);
// else score role (32 slots/wave, 8 per 16-lane quarter, full unroll).
// GEMM compute hides in score's gather-latency shadow; scores bit-compatible.
__global__ void k_score_g2h(const float* __restrict__ h1, const int2* __restrict__ csrp,
                            unsigned* __restrict__ scoreu_csr,
                            unsigned short* __restrict__ seg_csr, int* __restrict__ hist,
                            const float* __restrict__ Wl, const float* __restrict__ Wr,
                            const float* __restrict__ bl,
                            __hip_bfloat16* __restrict__ y, float* __restrict__ r) {
  __shared__ float sx[32][H];
  int lane = threadIdx.x, ty = threadIdx.y;
  int q3 = blockIdx.x / 3, r3 = blockIdx.x - q3 * 3;
  if (r3 == 0 && q3 < GB2) {
    // ---- gemm2h role: rows [q3*32, q3*32+32), guarded at N ----
    int tid = ty * 64 + lane;
    int row0 = q3 * 32;
    {
      int row = row0 + (tid >> 4);
      if (row < N)
        ((float4*)(&sx[0][0]))[tid] = ((const float4*)h1)[(size_t)row * (H / 4) + (tid & 15)];
    }
    __syncthreads();
    float al[4], ar[4];
    float bias = bl[lane];
#pragma unroll
    for (int j = 0; j < 4; ++j) { al[j] = 0.f; ar[j] = bias; }
#pragma unroll 4
    for (int f = 0; f < H; ++f) {
      float wl = Wl[f * H + lane];
      float wr = Wr[f * H + lane];
#pragma unroll
      for (int j = 0; j < 4; ++j) {
        float xv = sx[ty * 4 + j][f];
        al[j] += xv * wl;
        ar[j] += xv * wr;
      }
    }
#pragma unroll
    for (int j = 0; j < 4; ++j) {
      int row = row0 + ty * 4 + j;
      if (row < N) {
        y[(size_t)row * H + lane] = __float2bfloat16(al[j]);
        r[(size_t)row * H + lane] = ar[j];
      }
    }
  } else {
    // ---- score role ----
    int sid = blockIdx.x - (q3 + (r3 > 0 ? 1 : 0));   // gemm blocks before this one
    int q = lane >> 4, c = lane & 15;   // 4 quarters x 16 lanes; 16 x float4 = 256B row
    int s = (sid * 8 + ty) * 32 + q * 8;
    int2 se[8];
#pragma unroll
    for (int j = 0; j < 8; ++j) se[j] = csrp[s + j];
    float4 xr[8], yr[8];
#pragma unroll
    for (int j = 0; j < 8; ++j)
      xr[j] = ((const float4*)(h1 + (size_t)slot_src(se[j]) * H))[c];
#pragma unroll
    for (int j = 0; j < 8; ++j)
      yr[j] = ((const float4*)(h1 + (size_t)slot_dst(se[j]) * H))[c];
    float p[8];
#pragma unroll
    for (int j = 0; j < 8; ++j)
      p[j] = yr[j].x * xr[j].x + yr[j].y * xr[j].y + yr[j].z * xr[j].z + yr[j].w * xr[j].w;
#pragma unroll
    for (int d = 1; d < 16; d <<= 1) {
#pragma unroll
      for (int j = 0; j < 8; ++j) p[j] += __shfl_xor(p[j], d);
    }
    if (c == 0) {
#pragma unroll
      for (int j = 0; j < 8; ++j) {
        int g = slot_g(se[j]);
        unsigned u = __float_as_uint(p[j]);
        u = (u & 0x80000000u) ? ~u : (u | 0x80000000u);
        scoreu_csr[s + j] = u;
        seg_csr[s + j] = (unsigned short)g;
        atomicAdd(&hist[g * 256 + (int)(u >> 24)], 1);
      }
    }
  }
}

// ---- radix-select histogram for passes 1..2, x4 vectorized ----
__global__ void k_hist(const unsigned* __restrict__ scoreu, const unsigned short* __restrict__ seg,
                       const unsigned* __restrict__ prefix, int* __restrict__ hist, int pass) {
  int e = (blockIdx.x * 256 + threadIdx.x) * 4;
  if (e >= E) return;
  uint4 u4 = *(const uint4*)(scoreu + e);
  ushort4 s4 = *(const ushort4*)(seg + e);
  unsigned uu[4] = {u4.x, u4.y, u4.z, u4.w};
  int gg[4] = {(int)s4.x, (int)s4.y, (int)s4.z, (int)s4.w};
  int predshift = 32 - 8 * pass;
  int bshift = 24 - 8 * pass;
#pragma unroll
  for (int j = 0; j < 4; ++j) {
    unsigned u = uu[j];
    int g = gg[j];
    if ((u >> predshift) == (prefix[g] >> predshift))
      atomicAdd(&hist[g * 256 + (int)((u >> bshift) & 0xFFu)], 1);
  }
}

// ---- descending bucket select: one wave per graph ----
__global__ void k_scan(int* __restrict__ hist, unsigned* __restrict__ prefix,
                       int* __restrict__ krem, int pass) {
  int g = blockIdx.x;
  int lane = threadIdx.x;
  int4* row = (int4*)(hist + (size_t)g * 256);
  int4 v = row[lane];
  int vj[4] = {v.x, v.y, v.z, v.w};
  int s = v.x + v.y + v.z + v.w;
  int inc = s;
  for (int d = 1; d < 64; d <<= 1) {
    int t = __shfl_up(inc, d);
    if (lane >= d) inc += t;
  }
  int T = __shfl(inc, 63);
  int k = (pass == 0) ? ((T + 1) >> 1) : krem[g];   // pass 0: T = edges in graph
  int excl = inc - s;
  int pre[4] = {excl, excl + vj[0], excl + vj[0] + vj[1], excl + vj[0] + vj[1] + vj[2]};
  int bsel_l = -1, newk_l = 0;
  if (k > 0) {
    for (int j = 3; j >= 0; --j) {
      int suf = T - pre[j];
      if (suf >= k) { bsel_l = 4 * lane + j; newk_l = k - (suf - vj[j]); break; }
    }
  }
  unsigned long long mask = __ballot(bsel_l >= 0);
  int bsel = 255, newk = 0;
  if (k > 0 && mask) {
    int hi = 63 - __builtin_clzll(mask);
    bsel = __shfl(bsel_l, hi);
    newk = __shfl(newk_l, hi);
  }
  if (lane == 0) {
    unsigned base = (pass == 0) ? 0u : prefix[g];
    prefix[g] = base | ((unsigned)bsel << (24 - 8 * pass));
    krem[g] = newk;
  }
  row[lane] = make_int4(0, 0, 0, 0);
}

// ---- classify CSR slots vs 24-bit threshold, x4 vectorized.
// Weights are NOT materialized; consumers recompute uinv_score(scoreu) ----
__global__ void k_select(const unsigned* __restrict__ scoreu_csr,
                         const unsigned short* __restrict__ seg_csr,
                         const unsigned* __restrict__ thresh,
                         int* __restrict__ eqcnt, int* __restrict__ eqlist,
                         unsigned char* __restrict__ sel_csr) {
  int s = (blockIdx.x * 256 + threadIdx.x) * 4;
  if (s >= E) return;
  uint4 u4 = *(const uint4*)(scoreu_csr + s);
  ushort4 g4 = *(const ushort4*)(seg_csr + s);
  unsigned uu[4] = {u4.x, u4.y, u4.z, u4.w};
  int gg[4] = {(int)g4.x, (int)g4.y, (int)g4.z, (int)g4.w};
  unsigned char sl[4];
#pragma unroll
  for (int j = 0; j < 4; ++j) {
    unsigned u = uu[j];
    int g = gg[j];
    unsigned t = thresh[g];                 // top-24 bits, low 8 zero
    unsigned um = u & 0xffffff00u;
    unsigned char sel = 0;
    if (um > t) sel = 1;
    else if (um == t) {
      int slot = atomicAdd(&eqcnt[g], 1);
      if (slot < CAP) eqlist[g * CAP + slot] = s + j;
    }
    sl[j] = sel;
  }
  *(uchar4*)(sel_csr + s) = make_uchar4(sl[0], sl[1], sl[2], sl[3]);
}

// ---- resolve 24-bit ties: top-r by (score desc, original idx asc); r,c ~1-3 ----
__global__ void k_resolve(const int* __restrict__ krem, const int* __restrict__ eqcnt,
                          const int* __restrict__ eqlist, const int2* __restrict__ csrp,
                          const unsigned* __restrict__ scoreu_csr,
                          unsigned char* __restrict__ sel_csr) {
  int g = blockIdx.x * 256 + threadIdx.x;
  if (g >= G) return;
  int c = eqcnt[g]; if (c > CAP) c = CAP;
  int r = krem[g];  if (r > c) r = c;
  const int* lst = eqlist + g * CAP;
  unsigned last_u = 0u; int last_e = -1; bool first = true;
  for (int i = 0; i < r; ++i) {
    unsigned bu = 0u; int be = -1, bs = -1;
    for (int j = 0; j < c; ++j) {
      int slot = lst[j];
      unsigned u = scoreu_csr[slot];
      int eid = slot_eid(csrp[slot]);
      bool after = first || (u < last_u) || (u == last_u && eid > last_e);
      if (after && (bs < 0 || u > bu || (u == bu && eid < be))) { bu = u; be = eid; bs = slot; }
    }
    if (bs < 0) break;
    sel_csr[bs] = 1;
    last_u = bu; last_e = be; first = false;
  }
}

// ---- FUSED: per-node compact (no atomics; weight recomputed from scoreu)
// + sampled back-permute, role-split ----
__global__ void k_samp_comp(const unsigned char* __restrict__ sel,
                            const int2* __restrict__ csrp,
                            const unsigned* __restrict__ scoreu,
                            const int* __restrict__ off, int2* __restrict__ csr2,
                            int* __restrict__ cnt2,
                            const int* __restrict__ einv, float* __restrict__ sampled) {
  int lane = threadIdx.x, ty = threadIdx.y;
  if (blockIdx.x < N / 8) {
    // ---- compact role ----
    int node = blockIdx.x * 8 + ty;
    int s0 = off[node], s1 = off[node + 1];
    unsigned long long lt = ((unsigned long long)1 << lane) - 1;
    int cum = 0;
    for (int i0 = s0; i0 < s1; i0 += 64) {
      int i = i0 + lane;
      bool f = (i < s1) && sel[i];
      unsigned long long m = __ballot(f);
      if (f) {
        int rank = __popcll(m & lt);
        float w = uinv_score(scoreu[i]);
        csr2[s0 + cum + rank] = make_int2(slot_src(csrp[i]), __float_as_int(w));
      }
      cum += __popcll(m);
    }
    if (lane == 0) cnt2[node] = cum;
  } else {
    // ---- sampled role: coalesced write, L2 gather of sel bytes ----
    int tid = ty * 64 + lane;
    int e = ((blockIdx.x - N / 8) * 512 + tid) * 4;
    if (e >= E) return;
    int4 iv = *(const int4*)(einv + e);
    float4 o;
    o.x = (float)sel[iv.x];
    o.y = (float)sel[iv.y];
    o.z = (float)sel[iv.z];
    o.w = (float)sel[iv.w];
    *(float4*)(sampled + e) = o;
  }
}

// ---- fused mean-pool + MLP head + log_softmax: one block per graph, 8-way pool ----
__global__ void k_poolhead(const float* __restrict__ h3, const int* __restrict__ goff,
                           const float* __restrict__ W1, const float* __restrict__ b1,
                           const float* __restrict__ W2, const float* __restrict__ b2,
                           float* __restrict__ outp) {
  int g = blockIdx.x;
  int tid = threadIdx.x;
  int h = tid & 63, j = tid >> 6;   // 8 partial-sum lanes per column
  int s0 = goff[g], s1 = goff[g + 1];
  float a = 0.f;
  for (int n = s0 + j; n < s1; n += 8) a += h3[(size_t)n * H + h];
  __shared__ float sp[8][H];
  __shared__ float p[H], z1[H], z2[C];
  __shared__ float lse;
  sp[j][h] = a;
  __syncthreads();
  if (j == 0) {
    float s = sp[0][h] + sp[1][h] + sp[2][h] + sp[3][h]
            + sp[4][h] + sp[5][h] + sp[6][h] + sp[7][h];
    float inv = 1.f / fmaxf((float)(s1 - s0), 1.f);
    p[h] = s * inv;
  }
  __syncthreads();
  if (j == 0) {
    float acc = b1[h];
#pragma unroll 8
    for (int f = 0; f < H; ++f) acc += p[f] * W1[f * H + h];
    z1[h] = fmaxf(acc, 0.f);
  }
  __syncthreads();
  if (tid < C) {
    float a2 = b2[tid];
#pragma unroll 8
    for (int f = 0; f < H; ++f) a2 += z1[f] * W2[f * C + tid];
    z2[tid] = a2;
  }
  __syncthreads();
  if (tid == 0) {
    float m = z2[0];
    for (int c = 1; c < C; ++c) m = fmaxf(m, z2[c]);
    float s = 0.f;
    for (int c = 0; c < C; ++c) s += expf(z2[c] - m);
    lse = m + logf(s);
  }
  __syncthreads();
  if (tid < C) outp[(size_t)g * C + tid] = z2[tid] - lse;
}

extern "C" void kernel_launch(void* const* d_in, const int* in_sizes, int n_in,
                              void* d_out, int out_size, void* d_ws, size_t ws_size,
                              hipStream_t stream) {
  const float* x     = (const float*)d_in[0];
  const int*   ei    = (const int*)d_in[1];
  const int*   batch = (const int*)d_in[2];
  const float* W1l   = (const float*)d_in[3];
  const float* b1l   = (const float*)d_in[4];
  const float* W1r   = (const float*)d_in[5];
  const float* W2l   = (const float*)d_in[6];
  const float* b2l   = (const float*)d_in[7];
  const float* W2r   = (const float*)d_in[8];
  const float* W3l   = (const float*)d_in[9];
  const float* b3l   = (const float*)d_in[10];
  const float* W3r   = (const float*)d_in[11];
  const float* Wlin1 = (const float*)d_in[12];
  const float* blin1 = (const float*)d_in[13];
  const float* Wlin2 = (const float*)d_in[14];
  const float* blin2 = (const float*)d_in[15];

  const int* srcv = ei;        // edge_index row 0
  const int* dstv = ei + E;    // edge_index row 1

  float* out_ls   = (float*)d_out;       // 512*10 log_softmax
  float* out_samp = out_ls + G * C;      // 800000 sampled mask

  // ---- workspace carve (256B-aligned); zero-init block first, one memset ----
  char* w = (char*)d_ws;
  auto carve = [&](size_t bytes) { void* p = (void*)w; w += (bytes + 255) & ~(size_t)255; return p; };
  char* zbase   = w;
  int*      deg     = (int*)carve((size_t)N * 4);
  int*      eqcnt   = (int*)carve((size_t)G * 4);
  int*      hist    = (int*)carve((size_t)G * 256 * 4);
  size_t    zbytes  = (size_t)(w - zbase);
  float*    h1      = (float*)carve((size_t)N * H * 4);
  float*    h3      = (float*)carve((size_t)N * H * 4);
  float*    yb      = (float*)carve((size_t)N * H * 4);   // fp32 projected-left (layer 1)
  float*    rb      = (float*)carve((size_t)N * H * 4);   // fp32 projected-right (L1, then L2)
  float*    rb2     = (float*)carve((size_t)N * H * 4);   // fp32 projected-right (layer 3)
  __hip_bfloat16* ybh  = (__hip_bfloat16*)carve((size_t)N * H * 2);  // bf16 table (layer 2)
  __hip_bfloat16* ybh2 = (__hip_bfloat16*)carve((size_t)N * H * 2);  // bf16 table (layer 3)
  unsigned* scoreu_csr = (unsigned*)carve((size_t)E * 4);
  unsigned short* seg_csr = (unsigned short*)carve((size_t)E * 2);
  unsigned char* sel_csr = (unsigned char*)carve((size_t)E);
  int2*     csrp    = (int2*)carve((size_t)E * 8);        // packed 63-bit slot records
  int*      einv    = (int*)carve((size_t)E * 4);         // edge -> slot (sampled role)
  unsigned short* rank16 = (unsigned short*)carve((size_t)E * 2);  // per-edge rank in dst node
  int*      off     = (int*)carve((size_t)(N + 1) * 4);
  int*      cnt2    = (int*)carve((size_t)N * 4);
  int*      goff    = (int*)carve((size_t)(G + 1) * 4);
  unsigned* prefix  = (unsigned*)carve((size_t)G * 4);
  int*      krem    = (int*)carve((size_t)G * 4);
  int*      eqlist  = (int*)carve((size_t)G * CAP * 4);
  int*      bsum    = (int*)carve((size_t)16 * 4);
  int2*     csr2    = (int2*)carve((size_t)E * 8);        // compacted {src, w} at off[node]

  hipMemsetAsync(zbase, 0, zbytes, stream);

  // ---- deg (+ranks) + goff, then parallel scan ----
  k_deg_goff<<<512, 256, 0, stream>>>(dstv, batch, deg, goff, rank16);
  int nb = cdiv(N, 4096);   // 13
  k_scan_a<<<nb, 1024, 0, stream>>>(deg, off, bsum, N);
  k_scan_c<<<cdiv(N + 1, 256), 256, 0, stream>>>(off, bsum, N, nb);

  // ---- FUSED atomic-free fill + layer-1 gemm, 1:4 interleave ----
  k_fill_gemm<<<5 * NFB, dim3(64, 4), 0, stream>>>(srcv, dstv, rank16, batch, off,
                                                   csrp, einv,
                                                   x, W1l, W1r, b1l, yb, rb);

  // ---- layer-1 aggregation ----
  k_agg1<<<N / 8, dim3(64, 8), 0, stream>>>(yb, rb, csrp, off, h1);

  // ---- FUSED edge scores + layer-2 gemm2h (2:1 interleave), then radix top-k ----
  k_score_g2h<<<SB + GB2, dim3(64, 8), 0, stream>>>(h1, csrp, scoreu_csr, seg_csr, hist,
                                                    W2l, W2r, b2l, ybh, rb);
  k_scan<<<G, 64, 0, stream>>>(hist, prefix, krem, 0);
  for (int p = 1; p <= 2; ++p) {
    k_hist<<<cdiv(E / 4, 256), 256, 0, stream>>>(scoreu_csr, seg_csr, prefix, hist, p);
    k_scan<<<G, 64, 0, stream>>>(hist, prefix, krem, p);
  }
  k_select<<<cdiv(E / 4, 256), 256, 0, stream>>>(scoreu_csr, seg_csr, prefix,
                                                 eqcnt, eqlist, sel_csr);
  k_resolve<<<cdiv(G, 256), 256, 0, stream>>>(krem, eqcnt, eqlist, csrp, scoreu_csr,
                                              sel_csr);

  // ---- FUSED compact (weights from scoreu) + sampled back-permute ----
  k_samp_comp<<<N / 8 + cdiv(E / 4, 512), dim3(64, 8), 0, stream>>>(
      sel_csr, csrp, scoreu_csr, off, csr2, cnt2, einv, out_samp);

  // ---- FUSED layer-2 aggregation + layer-3 projections (h2 never hits memory) ----
  k_agg_w_p3<<<N / 8, dim3(64, 8), 0, stream>>>(ybh, rb, csr2, cnt2, off, scoreu_csr,
                                                W3l, W3r, b3l, ybh2, rb2);

  // ---- layer 3 aggregation ----
  k_agg_w<<<N / 8, dim3(64, 8), 0, stream>>>(ybh2, rb2, csr2, cnt2, off, h3);

  // ---- fused pool + head ----
  k_poolhead<<<G, 512, 0, stream>>>(h3, goff, Wlin1, blin1, Wlin2, blin2, out_ls);
}

// Round 13
// 402.237 us; speedup vs baseline: 1.0551x; 1.0551x over previous
//
#include <hip/hip_runtime.h>
#include <hip/hip_bf16.h>
#include <math.h>

static constexpr int N = 50000;
static constexpr int E = 800000;
static constexpr int F = 128;
static constexpr int H = 64;
static constexpr int G = 512;
static constexpr int C = 10;
static constexpr int CAP = 256;    // per-graph capacity for 24-bit-tied edges (~1-3 expected)
static constexpr int NFB = (E / 4 + 255) / 256;   // 782 fill blocks (int4-granular, guarded)
static constexpr int GB1 = N / 16;        // 3125 layer-1 gemm blocks (16 rows)
static constexpr int GB2 = (N + 31) / 32; // 1563 layer-2 gemm blocks (32 rows, guarded)
static constexpr int SB = E / 256;        // 3125 score blocks

static inline int cdiv(long a, int b) { return (int)((a + b - 1) / b); }

__device__ __forceinline__ float uinv_score(unsigned u) {
  // inverse of the order-preserving float->uint map
  return (u & 0x80000000u) ? __uint_as_float(u & 0x7fffffffu) : __uint_as_float(~u);
}

// ---- packed slot record: 63 bits in int2 ----
// a = src(17) | dst_lo15(15)<<17 ; b = dst_hi2(2) | g(9)<<2 | eid(20)<<11
__device__ __forceinline__ int2 pack_slot(int s, int d, int g, int e) {
  unsigned a = (unsigned)s | ((unsigned)(d & 0x7FFF) << 17);
  unsigned b = ((unsigned)d >> 15) | ((unsigned)g << 2) | ((unsigned)e << 11);
  return make_int2((int)a, (int)b);
}
__device__ __forceinline__ int slot_src(int2 p) { return p.x & 0x1FFFF; }
__device__ __forceinline__ int slot_dst(int2 p) {
  return (int)(((unsigned)p.x >> 17) | (((unsigned)p.y & 3u) << 15));
}
__device__ __forceinline__ int slot_g(int2 p) { return (int)(((unsigned)p.y >> 2) & 0x1FFu); }
__device__ __forceinline__ int slot_eid(int2 p) { return (int)((unsigned)p.y >> 11); }

// ---- deg (in-deg over dst, int4 x4-ILP atomics) + goff boundaries + RANKS.
// The atomicAdd RETURN VALUE is each edge's rank within its dst node — stored
// to rank16[e] (coalesced ushort4). This lets the fill pass compute its slot
// as off[d]+rank with NO atomics.
__global__ void k_deg_goff(const int* __restrict__ dst, const int* __restrict__ batch,
                           int* __restrict__ deg, int* __restrict__ goff,
                           unsigned short* __restrict__ rank16) {
  int tid = threadIdx.x;
  for (int i = blockIdx.x * 256 + tid; i < N; i += gridDim.x * 256) {
    int b = batch[i];
    if (i == 0) {
      for (int g = 0; g <= b; ++g) goff[g] = 0;
    } else {
      int p = batch[i - 1];
      for (int g = p + 1; g <= b; ++g) goff[g] = i;
    }
    if (i == N - 1) {
      for (int g = b + 1; g <= G; ++g) goff[g] = N;
    }
  }
  const int4* d4 = (const int4*)dst;
  for (int i = blockIdx.x * 256 + tid; i < E / 4; i += gridDim.x * 256) {
    int4 v = d4[i];
    ushort4 rk;
    rk.x = (unsigned short)atomicAdd(&deg[v.x], 1);
    rk.y = (unsigned short)atomicAdd(&deg[v.y], 1);
    rk.z = (unsigned short)atomicAdd(&deg[v.z], 1);
    rk.w = (unsigned short)atomicAdd(&deg[v.w], 1);
    *(ushort4*)(rank16 + (size_t)i * 4) = rk;
  }
}

// ---- parallel exclusive scan, 2 kernels (block-sum scan folded into pass c) ----
__global__ void k_scan_a(const int* __restrict__ cnt, int* __restrict__ off,
                         int* __restrict__ bsum, int n) {
  __shared__ int wsum[16];
  int tid = threadIdx.x, lane = tid & 63, wv = tid >> 6;
  int idx = blockIdx.x * 4096 + tid * 4;
  int v0 = (idx + 0 < n) ? cnt[idx + 0] : 0;
  int v1 = (idx + 1 < n) ? cnt[idx + 1] : 0;
  int v2 = (idx + 2 < n) ? cnt[idx + 2] : 0;
  int v3 = (idx + 3 < n) ? cnt[idx + 3] : 0;
  int local = v0 + v1 + v2 + v3;
  int inc = local;
  for (int d = 1; d < 64; d <<= 1) {
    int t = __shfl_up(inc, d);
    if (lane >= d) inc += t;
  }
  if (lane == 63) wsum[wv] = inc;
  __syncthreads();
  if (tid < 16) {
    int t = wsum[tid];
    for (int d = 1; d < 16; d <<= 1) {
      int u = __shfl_up(t, d);
      if (tid >= d) t += u;
    }
    wsum[tid] = t;
  }
  __syncthreads();
  int woff = (wv > 0) ? wsum[wv - 1] : 0;
  int excl = woff + inc - local;
  if (idx + 0 < n) off[idx + 0] = excl;
  if (idx + 1 < n) off[idx + 1] = excl + v0;
  if (idx + 2 < n) off[idx + 2] = excl + v0 + v1;
  if (idx + 3 < n) off[idx + 3] = excl + v0 + v1 + v2;
  if (tid == 0) bsum[blockIdx.x] = wsum[15];
}

// adds block-sum prefix; every block redundantly scans the <=32 block sums (cheap)
__global__ void k_scan_c(int* __restrict__ off, const int* __restrict__ bsum, int n, int nb) {
  __shared__ int spre[34];
  int tid = threadIdx.x;
  if (tid < 32) {
    int v = (tid < nb) ? bsum[tid] : 0;
    int inc = v;
    for (int d = 1; d < 32; d <<= 1) {
      int t = __shfl_up(inc, d);
      if (tid >= d) inc += t;
    }
    spre[tid] = inc - v;   // exclusive; spre[nb] = total
  }
  __syncthreads();
  int i = blockIdx.x * 256 + tid;
  if (i < n) {
    off[i] = off[i] + spre[i >> 12];
  } else if (i == n) {
    off[n] = spre[nb];
  }
}

// ---- FUSED: atomic-free rank-based fill + layer-1 dense GEMM, 1:4 interleave.
// blockIdx%5==0 -> fill role: slot = off[dst] + rank16[e] (no RMW, single
// linear int4 pass; scatter csrp 8B + coalesced einv int4).
// else -> gemm role (y=x@W1l, r=x@W1r+b, 16 rows) hiding in fill's shadow.
__global__ void k_fill_gemm(const int* __restrict__ src, const int* __restrict__ dst,
                            const unsigned short* __restrict__ rank16,
                            const int* __restrict__ batch, const int* __restrict__ off,
                            int2* __restrict__ csrp, int* __restrict__ einv,
                            const float* __restrict__ x, const float* __restrict__ Wl,
                            const float* __restrict__ Wr, const float* __restrict__ bl,
                            float* __restrict__ y, float* __restrict__ r) {
  __shared__ float sx[16][F];
  int lane = threadIdx.x, ty = threadIdx.y;
  int tid = ty * 64 + lane;
  int bq = blockIdx.x / 5, br = blockIdx.x - bq * 5;
  if (br == 0) {
    // ---- fill role: int4 index i covers edges [4i, 4i+4) ----
    int i = bq * 256 + tid;
    if (i < E / 4) {
      int4 dv = ((const int4*)dst)[i];
      int4 sv = ((const int4*)src)[i];
      ushort4 rv = *(const ushort4*)(rank16 + (size_t)i * 4);
      int dd[4] = {dv.x, dv.y, dv.z, dv.w};
      int ss[4] = {sv.x, sv.y, sv.z, sv.w};
      int rr[4] = {rv.x, rv.y, rv.z, rv.w};
      int e0 = i * 4;
      int slots[4];
#pragma unroll
      for (int j = 0; j < 4; ++j) {
        int g = batch[ss[j]];
        int slot = off[dd[j]] + rr[j];
        csrp[slot] = pack_slot(ss[j], dd[j], g, e0 + j);
        slots[j] = slot;
      }
      *(int4*)(einv + e0) = make_int4(slots[0], slots[1], slots[2], slots[3]);
    }
    return;
  }
  // ---- gemm role: rows [gid*16, gid*16+16) ----
  int gid = bq * 4 + (br - 1);
  if (gid >= GB1) return;
  int row0 = gid * 16;
  const float4* gsrc = (const float4*)(x + (size_t)row0 * F);
  float4* sdst = (float4*)(&sx[0][0]);
#pragma unroll
  for (int i = tid; i < 16 * F / 4; i += 256) sdst[i] = gsrc[i];
  __syncthreads();
  float al[4], ar[4];
  float bias = bl[lane];
#pragma unroll
  for (int j = 0; j < 4; ++j) { al[j] = 0.f; ar[j] = bias; }
#pragma unroll 4
  for (int f = 0; f < F; ++f) {
    float wl = Wl[f * H + lane];
    float wr = Wr[f * H + lane];
#pragma unroll
    for (int j = 0; j < 4; ++j) {
      float xv = sx[ty * 4 + j][f];
      al[j] += xv * wl;
      ar[j] += xv * wr;
    }
  }
#pragma unroll
  for (int j = 0; j < 4; ++j) {
    int row = row0 + ty * 4 + j;
    y[(size_t)row * H + lane] = al[j];
    r[(size_t)row * H + lane] = ar[j];
  }
}

// ---- dense pre-GEMM (bf16 y table): layer 3 standalone ----
template <int K>
__global__ void k_gemm2h(const float* __restrict__ in, const float* __restrict__ Wl,
                         const float* __restrict__ Wr, const float* __restrict__ b,
                         __hip_bfloat16* __restrict__ y, float* __restrict__ r) {
  __shared__ float sx[16][K];
  int lane = threadIdx.x, ty = threadIdx.y;
  int tid = ty * 64 + lane;
  int row0 = blockIdx.x * 16;
  const float4* gsrc = (const float4*)(in + (size_t)row0 * K);
  float4* sdst = (float4*)(&sx[0][0]);
#pragma unroll
  for (int i = tid; i < 16 * K / 4; i += 256) sdst[i] = gsrc[i];
  __syncthreads();
  float al[4], ar[4];
  float bias = b[lane];
#pragma unroll
  for (int j = 0; j < 4; ++j) { al[j] = 0.f; ar[j] = bias; }
#pragma unroll 4
  for (int f = 0; f < K; ++f) {
    float wl = Wl[f * H + lane];
    float wr = Wr[f * H + lane];
#pragma unroll
    for (int j = 0; j < 4; ++j) {
      float xv = sx[ty * 4 + j][f];
      al[j] += xv * wl;
      ar[j] += xv * wr;
    }
  }
#pragma unroll
  for (int j = 0; j < 4; ++j) {
    int row = row0 + ty * 4 + j;
    y[(size_t)row * H + lane] = __float2bfloat16(al[j]);
    r[(size_t)row * H + lane] = ar[j];
  }
}

// ---- layer-1 aggregation (fp32 rows): eighth-wave per edge ----
__global__ void k_agg1(const float* __restrict__ y, const float* __restrict__ r,
                       const int2* __restrict__ csrp, const int* __restrict__ off,
                       float* __restrict__ out) {
  int node = blockIdx.x * 8 + threadIdx.y;
  int lane = threadIdx.x;
  int q = lane >> 3, c = lane & 7;
  int s0 = off[node], s1 = off[node + 1];
  float4 a0 = make_float4(0.f, 0.f, 0.f, 0.f);
  float4 a1 = make_float4(0.f, 0.f, 0.f, 0.f);
  int i = s0 + q;
  for (; i + 8 < s1; i += 16) {
    int se0 = slot_src(csrp[i]);
    int se1 = slot_src(csrp[i + 8]);
    const float4* p0 = (const float4*)(y + (size_t)se0 * H);
    const float4* p1 = (const float4*)(y + (size_t)se1 * H);
    float4 u0 = p0[c], v0 = p0[c + 8];
    float4 u1 = p1[c], v1 = p1[c + 8];
    a0.x += u0.x + u1.x; a0.y += u0.y + u1.y; a0.z += u0.z + u1.z; a0.w += u0.w + u1.w;
    a1.x += v0.x + v1.x; a1.y += v0.y + v1.y; a1.z += v0.z + v1.z; a1.w += v0.w + v1.w;
  }
  for (; i < s1; i += 8) {
    int se = slot_src(csrp[i]);
    const float4* p = (const float4*)(y + (size_t)se * H);
    float4 u = p[c], v = p[c + 8];
    a0.x += u.x; a0.y += u.y; a0.z += u.z; a0.w += u.w;
    a1.x += v.x; a1.y += v.y; a1.z += v.z; a1.w += v.w;
  }
#pragma unroll
  for (int d = 8; d < 64; d <<= 1) {
    a0.x += __shfl_xor(a0.x, d); a0.y += __shfl_xor(a0.y, d);
    a0.z += __shfl_xor(a0.z, d); a0.w += __shfl_xor(a0.w, d);
    a1.x += __shfl_xor(a1.x, d); a1.y += __shfl_xor(a1.y, d);
    a1.z += __shfl_xor(a1.z, d); a1.w += __shfl_xor(a1.w, d);
  }
  if (q == 0) {
    float inv = 1.f / fmaxf((float)(s1 - s0), 1.f);
    const float4* rp = (const float4*)(r + (size_t)node * H);
    float4 r0 = rp[c], r1 = rp[c + 8];
    float4 o0, o1;
    o0.x = fmaxf(a0.x * inv + r0.x, 0.f); o0.y = fmaxf(a0.y * inv + r0.y, 0.f);
    o0.z = fmaxf(a0.z * inv + r0.z, 0.f); o0.w = fmaxf(a0.w * inv + r0.w, 0.f);
    o1.x = fmaxf(a1.x * inv + r1.x, 0.f); o1.y = fmaxf(a1.y * inv + r1.y, 0.f);
    o1.z = fmaxf(a1.z * inv + r1.z, 0.f); o1.w = fmaxf(a1.w * inv + r1.w, 0.f);
    float4* op = (float4*)(out + (size_t)node * H);
    op[c] = o0; op[c + 8] = o1;
  }
}

// ---- weighted aggregation over COMPACTED edges (bf16 rows): eighth-wave ----
__global__ void k_agg_w(const __hip_bfloat16* __restrict__ y, const float* __restrict__ r,
                        const int2* __restrict__ csr2, const int* __restrict__ cnt2,
                        const int* __restrict__ off, float* __restrict__ out) {
  int node = blockIdx.x * 8 + threadIdx.y;
  int lane = threadIdx.x;
  int q = lane >> 3, c = lane & 7;
  int b0 = off[node], cn = cnt2[node];
  float a[8] = {0.f, 0.f, 0.f, 0.f, 0.f, 0.f, 0.f, 0.f};
  for (int j = q; j < cn; j += 8) {
    int2 sw = csr2[b0 + j];
    float w = __int_as_float(sw.y);
    uint4 pk = ((const uint4*)((const unsigned short*)y + (size_t)sw.x * H))[c];
    a[0] += w * __uint_as_float(pk.x << 16); a[1] += w * __uint_as_float(pk.x & 0xffff0000u);
    a[2] += w * __uint_as_float(pk.y << 16); a[3] += w * __uint_as_float(pk.y & 0xffff0000u);
    a[4] += w * __uint_as_float(pk.z << 16); a[5] += w * __uint_as_float(pk.z & 0xffff0000u);
    a[6] += w * __uint_as_float(pk.w << 16); a[7] += w * __uint_as_float(pk.w & 0xffff0000u);
  }
#pragma unroll
  for (int d = 8; d < 64; d <<= 1) {
#pragma unroll
    for (int j = 0; j < 8; ++j) a[j] += __shfl_xor(a[j], d);
  }
  if (q == 0) {
    int degn = off[node + 1] - off[node];
    float inv = 1.f / fmaxf((float)degn, 1.f);
    const float4* rp = (const float4*)(r + (size_t)node * H);
    float4 r0 = rp[2 * c], r1 = rp[2 * c + 1];
    float4 o0, o1;
    o0.x = fmaxf(a[0] * inv + r0.x, 0.f); o0.y = fmaxf(a[1] * inv + r0.y, 0.f);
    o0.z = fmaxf(a[2] * inv + r0.z, 0.f); o0.w = fmaxf(a[3] * inv + r0.w, 0.f);
    o1.x = fmaxf(a[4] * inv + r1.x, 0.f); o1.y = fmaxf(a[5] * inv + r1.y, 0.f);
    o1.z = fmaxf(a[6] * inv + r1.z, 0.f); o1.w = fmaxf(a[7] * inv + r1.w, 0.f);
    float4* op = (float4*)(out + (size_t)node * H);
    op[2 * c] = o0; op[2 * c + 1] = o1;
  }
}

// ---- FUSED: edge-slot-parallel scoring + layer-2 bf16 GEMM, interleaved 2:1.
// blockIdx%3==0 -> gemm2h role (32 rows of h1@W2l / h1@W2r+b2l, guarded);
// else score role (32 slots/wave, 8 per 16-lane quarter, full unroll).
// GEMM compute hides in score's gather-latency shadow; scores bit-compatible.
__global__ void k_score_g2h(const float* __restrict__ h1, const int2* __restrict__ csrp,
                            unsigned* __restrict__ scoreu_csr,
                            unsigned short* __restrict__ seg_csr, int* __restrict__ hist,
                            const float* __restrict__ Wl, const float* __restrict__ Wr,
                            const float* __restrict__ bl,
                            __hip_bfloat16* __restrict__ y, float* __restrict__ r) {
  __shared__ float sx[32][H];
  int lane = threadIdx.x, ty = threadIdx.y;
  int q3 = blockIdx.x / 3, r3 = blockIdx.x - q3 * 3;
  if (r3 == 0 && q3 < GB2) {
    // ---- gemm2h role: rows [q3*32, q3*32+32), guarded at N ----
    int tid = ty * 64 + lane;
    int row0 = q3 * 32;
    {
      int row = row0 + (tid >> 4);
      if (row < N)
        ((float4*)(&sx[0][0]))[tid] = ((const float4*)h1)[(size_t)row * (H / 4) + (tid & 15)];
    }
    __syncthreads();
    float al[4], ar[4];
    float bias = bl[lane];
#pragma unroll
    for (int j = 0; j < 4; ++j) { al[j] = 0.f; ar[j] = bias; }
#pragma unroll 4
    for (int f = 0; f < H; ++f) {
      float wl = Wl[f * H + lane];
      float wr = Wr[f * H + lane];
#pragma unroll
      for (int j = 0; j < 4; ++j) {
        float xv = sx[ty * 4 + j][f];
        al[j] += xv * wl;
        ar[j] += xv * wr;
      }
    }
#pragma unroll
    for (int j = 0; j < 4; ++j) {
      int row = row0 + ty * 4 + j;
      if (row < N) {
        y[(size_t)row * H + lane] = __float2bfloat16(al[j]);
        r[(size_t)row * H + lane] = ar[j];
      }
    }
  } else {
    // ---- score role ----
    int sid = blockIdx.x - (q3 + (r3 > 0 ? 1 : 0));   // gemm blocks before this one
    int q = lane >> 4, c = lane & 15;   // 4 quarters x 16 lanes; 16 x float4 = 256B row
    int s = (sid * 8 + ty) * 32 + q * 8;
    int2 se[8];
#pragma unroll
    for (int j = 0; j < 8; ++j) se[j] = csrp[s + j];
    float4 xr[8], yr[8];
#pragma unroll
    for (int j = 0; j < 8; ++j)
      xr[j] = ((const float4*)(h1 + (size_t)slot_src(se[j]) * H))[c];
#pragma unroll
    for (int j = 0; j < 8; ++j)
      yr[j] = ((const float4*)(h1 + (size_t)slot_dst(se[j]) * H))[c];
    float p[8];
#pragma unroll
    for (int j = 0; j < 8; ++j)
      p[j] = yr[j].x * xr[j].x + yr[j].y * xr[j].y + yr[j].z * xr[j].z + yr[j].w * xr[j].w;
#pragma unroll
    for (int d = 1; d < 16; d <<= 1) {
#pragma unroll
      for (int j = 0; j < 8; ++j) p[j] += __shfl_xor(p[j], d);
    }
    if (c == 0) {
#pragma unroll
      for (int j = 0; j < 8; ++j) {
        int g = slot_g(se[j]);
        unsigned u = __float_as_uint(p[j]);
        u = (u & 0x80000000u) ? ~u : (u | 0x80000000u);
        scoreu_csr[s + j] = u;
        seg_csr[s + j] = (unsigned short)g;
        atomicAdd(&hist[g * 256 + (int)(u >> 24)], 1);
      }
    }
  }
}

// ---- radix-select histogram for passes 1..2, x4 vectorized ----
__global__ void k_hist(const unsigned* __restrict__ scoreu, const unsigned short* __restrict__ seg,
                       const unsigned* __restrict__ prefix, int* __restrict__ hist, int pass) {
  int e = (blockIdx.x * 256 + threadIdx.x) * 4;
  if (e >= E) return;
  uint4 u4 = *(const uint4*)(scoreu + e);
  ushort4 s4 = *(const ushort4*)(seg + e);
  unsigned uu[4] = {u4.x, u4.y, u4.z, u4.w};
  int gg[4] = {(int)s4.x, (int)s4.y, (int)s4.z, (int)s4.w};
  int predshift = 32 - 8 * pass;
  int bshift = 24 - 8 * pass;
#pragma unroll
  for (int j = 0; j < 4; ++j) {
    unsigned u = uu[j];
    int g = gg[j];
    if ((u >> predshift) == (prefix[g] >> predshift))
      atomicAdd(&hist[g * 256 + (int)((u >> bshift) & 0xFFu)], 1);
  }
}

// ---- descending bucket select: one wave per graph ----
__global__ void k_scan(int* __restrict__ hist, unsigned* __restrict__ prefix,
                       int* __restrict__ krem, int pass) {
  int g = blockIdx.x;
  int lane = threadIdx.x;
  int4* row = (int4*)(hist + (size_t)g * 256);
  int4 v = row[lane];
  int vj[4] = {v.x, v.y, v.z, v.w};
  int s = v.x + v.y + v.z + v.w;
  int inc = s;
  for (int d = 1; d < 64; d <<= 1) {
    int t = __shfl_up(inc, d);
    if (lane >= d) inc += t;
  }
  int T = __shfl(inc, 63);
  int k = (pass == 0) ? ((T + 1) >> 1) : krem[g];   // pass 0: T = edges in graph
  int excl = inc - s;
  int pre[4] = {excl, excl + vj[0], excl + vj[0] + vj[1], excl + vj[0] + vj[1] + vj[2]};
  int bsel_l = -1, newk_l = 0;
  if (k > 0) {
    for (int j = 3; j >= 0; --j) {
      int suf = T - pre[j];
      if (suf >= k) { bsel_l = 4 * lane + j; newk_l = k - (suf - vj[j]); break; }
    }
  }
  unsigned long long mask = __ballot(bsel_l >= 0);
  int bsel = 255, newk = 0;
  if (k > 0 && mask) {
    int hi = 63 - __builtin_clzll(mask);
    bsel = __shfl(bsel_l, hi);
    newk = __shfl(newk_l, hi);
  }
  if (lane == 0) {
    unsigned base = (pass == 0) ? 0u : prefix[g];
    prefix[g] = base | ((unsigned)bsel << (24 - 8 * pass));
    krem[g] = newk;
  }
  row[lane] = make_int4(0, 0, 0, 0);
}

// ---- classify CSR slots vs 24-bit threshold, x4 vectorized.
// Weights are NOT materialized; consumers recompute uinv_score(scoreu) ----
__global__ void k_select(const unsigned* __restrict__ scoreu_csr,
                         const unsigned short* __restrict__ seg_csr,
                         const unsigned* __restrict__ thresh,
                         int* __restrict__ eqcnt, int* __restrict__ eqlist,
                         unsigned char* __restrict__ sel_csr) {
  int s = (blockIdx.x * 256 + threadIdx.x) * 4;
  if (s >= E) return;
  uint4 u4 = *(const uint4*)(scoreu_csr + s);
  ushort4 g4 = *(const ushort4*)(seg_csr + s);
  unsigned uu[4] = {u4.x, u4.y, u4.z, u4.w};
  int gg[4] = {(int)g4.x, (int)g4.y, (int)g4.z, (int)g4.w};
  unsigned char sl[4];
#pragma unroll
  for (int j = 0; j < 4; ++j) {
    unsigned u = uu[j];
    int g = gg[j];
    unsigned t = thresh[g];                 // top-24 bits, low 8 zero
    unsigned um = u & 0xffffff00u;
    unsigned char sel = 0;
    if (um > t) sel = 1;
    else if (um == t) {
      int slot = atomicAdd(&eqcnt[g], 1);
      if (slot < CAP) eqlist[g * CAP + slot] = s + j;
    }
    sl[j] = sel;
  }
  *(uchar4*)(sel_csr + s) = make_uchar4(sl[0], sl[1], sl[2], sl[3]);
}

// ---- resolve 24-bit ties: top-r by (score desc, original idx asc); r,c ~1-3 ----
__global__ void k_resolve(const int* __restrict__ krem, const int* __restrict__ eqcnt,
                          const int* __restrict__ eqlist, const int2* __restrict__ csrp,
                          const unsigned* __restrict__ scoreu_csr,
                          unsigned char* __restrict__ sel_csr) {
  int g = blockIdx.x * 256 + threadIdx.x;
  if (g >= G) return;
  int c = eqcnt[g]; if (c > CAP) c = CAP;
  int r = krem[g];  if (r > c) r = c;
  const int* lst = eqlist + g * CAP;
  unsigned last_u = 0u; int last_e = -1; bool first = true;
  for (int i = 0; i < r; ++i) {
    unsigned bu = 0u; int be = -1, bs = -1;
    for (int j = 0; j < c; ++j) {
      int slot = lst[j];
      unsigned u = scoreu_csr[slot];
      int eid = slot_eid(csrp[slot]);
      bool after = first || (u < last_u) || (u == last_u && eid > last_e);
      if (after && (bs < 0 || u > bu || (u == bu && eid < be))) { bu = u; be = eid; bs = slot; }
    }
    if (bs < 0) break;
    sel_csr[bs] = 1;
    last_u = bu; last_e = be; first = false;
  }
}

// ---- FUSED: per-node compact (no atomics; weight recomputed from scoreu)
// + sampled back-permute, role-split ----
__global__ void k_samp_comp(const unsigned char* __restrict__ sel,
                            const int2* __restrict__ csrp,
                            const unsigned* __restrict__ scoreu,
                            const int* __restrict__ off, int2* __restrict__ csr2,
                            int* __restrict__ cnt2,
                            const int* __restrict__ einv, float* __restrict__ sampled) {
  int lane = threadIdx.x, ty = threadIdx.y;
  if (blockIdx.x < N / 8) {
    // ---- compact role ----
    int node = blockIdx.x * 8 + ty;
    int s0 = off[node], s1 = off[node + 1];
    unsigned long long lt = ((unsigned long long)1 << lane) - 1;
    int cum = 0;
    for (int i0 = s0; i0 < s1; i0 += 64) {
      int i = i0 + lane;
      bool f = (i < s1) && sel[i];
      unsigned long long m = __ballot(f);
      if (f) {
        int rank = __popcll(m & lt);
        float w = uinv_score(scoreu[i]);
        csr2[s0 + cum + rank] = make_int2(slot_src(csrp[i]), __float_as_int(w));
      }
      cum += __popcll(m);
    }
    if (lane == 0) cnt2[node] = cum;
  } else {
    // ---- sampled role: coalesced write, L2 gather of sel bytes ----
    int tid = ty * 64 + lane;
    int e = ((blockIdx.x - N / 8) * 512 + tid) * 4;
    if (e >= E) return;
    int4 iv = *(const int4*)(einv + e);
    float4 o;
    o.x = (float)sel[iv.x];
    o.y = (float)sel[iv.y];
    o.z = (float)sel[iv.z];
    o.w = (float)sel[iv.w];
    *(float4*)(sampled + e) = o;
  }
}

// ---- fused mean-pool + MLP head + log_softmax: one block per graph, 8-way pool ----
__global__ void k_poolhead(const float* __restrict__ h3, const int* __restrict__ goff,
                           const float* __restrict__ W1, const float* __restrict__ b1,
                           const float* __restrict__ W2, const float* __restrict__ b2,
                           float* __restrict__ outp) {
  int g = blockIdx.x;
  int tid = threadIdx.x;
  int h = tid & 63, j = tid >> 6;   // 8 partial-sum lanes per column
  int s0 = goff[g], s1 = goff[g + 1];
  float a = 0.f;
  for (int n = s0 + j; n < s1; n += 8) a += h3[(size_t)n * H + h];
  __shared__ float sp[8][H];
  __shared__ float p[H], z1[H], z2[C];
  __shared__ float lse;
  sp[j][h] = a;
  __syncthreads();
  if (j == 0) {
    float s = sp[0][h] + sp[1][h] + sp[2][h] + sp[3][h]
            + sp[4][h] + sp[5][h] + sp[6][h] + sp[7][h];
    float inv = 1.f / fmaxf((float)(s1 - s0), 1.f);
    p[h] = s * inv;
  }
  __syncthreads();
  if (j == 0) {
    float acc = b1[h];
#pragma unroll 8
    for (int f = 0; f < H; ++f) acc += p[f] * W1[f * H + h];
    z1[h] = fmaxf(acc, 0.f);
  }
  __syncthreads();
  if (tid < C) {
    float a2 = b2[tid];
#pragma unroll 8
    for (int f = 0; f < H; ++f) a2 += z1[f] * W2[f * C + tid];
    z2[tid] = a2;
  }
  __syncthreads();
  if (tid == 0) {
    float m = z2[0];
    for (int c = 1; c < C; ++c) m = fmaxf(m, z2[c]);
    float s = 0.f;
    for (int c = 0; c < C; ++c) s += expf(z2[c] - m);
    lse = m + logf(s);
  }
  __syncthreads();
  if (tid < C) outp[(size_t)g * C + tid] = z2[tid] - lse;
}

extern "C" void kernel_launch(void* const* d_in, const int* in_sizes, int n_in,
                              void* d_out, int out_size, void* d_ws, size_t ws_size,
                              hipStream_t stream) {
  const float* x     = (const float*)d_in[0];
  const int*   ei    = (const int*)d_in[1];
  const int*   batch = (const int*)d_in[2];
  const float* W1l   = (const float*)d_in[3];
  const float* b1l   = (const float*)d_in[4];
  const float* W1r   = (const float*)d_in[5];
  const float* W2l   = (const float*)d_in[6];
  const float* b2l   = (const float*)d_in[7];
  const float* W2r   = (const float*)d_in[8];
  const float* W3l   = (const float*)d_in[9];
  const float* b3l   = (const float*)d_in[10];
  const float* W3r   = (const float*)d_in[11];
  const float* Wlin1 = (const float*)d_in[12];
  const float* blin1 = (const float*)d_in[13];
  const float* Wlin2 = (const float*)d_in[14];
  const float* blin2 = (const float*)d_in[15];

  const int* srcv = ei;        // edge_index row 0
  const int* dstv = ei + E;    // edge_index row 1

  float* out_ls   = (float*)d_out;       // 512*10 log_softmax
  float* out_samp = out_ls + G * C;      // 800000 sampled mask

  // ---- workspace carve (256B-aligned); zero-init block first, one memset ----
  char* w = (char*)d_ws;
  auto carve = [&](size_t bytes) { void* p = (void*)w; w += (bytes + 255) & ~(size_t)255; return p; };
  char* zbase   = w;
  int*      deg     = (int*)carve((size_t)N * 4);
  int*      eqcnt   = (int*)carve((size_t)G * 4);
  int*      hist    = (int*)carve((size_t)G * 256 * 4);
  size_t    zbytes  = (size_t)(w - zbase);
  float*    h1      = (float*)carve((size_t)N * H * 4);
  float*    h2      = (float*)carve((size_t)N * H * 4);
  float*    h3      = (float*)carve((size_t)N * H * 4);
  float*    yb      = (float*)carve((size_t)N * H * 4);   // fp32 projected-left (layer 1)
  float*    rb      = (float*)carve((size_t)N * H * 4);   // fp32 projected-right
  __hip_bfloat16* ybh = (__hip_bfloat16*)carve((size_t)N * H * 2);  // bf16 table (layers 2/3)
  unsigned* scoreu_csr = (unsigned*)carve((size_t)E * 4);
  unsigned short* seg_csr = (unsigned short*)carve((size_t)E * 2);
  unsigned char* sel_csr = (unsigned char*)carve((size_t)E);
  int2*     csrp    = (int2*)carve((size_t)E * 8);        // packed 63-bit slot records
  int*      einv    = (int*)carve((size_t)E * 4);         // edge -> slot (sampled role)
  unsigned short* rank16 = (unsigned short*)carve((size_t)E * 2);  // per-edge rank in dst node
  int*      off     = (int*)carve((size_t)(N + 1) * 4);
  int*      cnt2    = (int*)carve((size_t)N * 4);
  int*      goff    = (int*)carve((size_t)(G + 1) * 4);
  unsigned* prefix  = (unsigned*)carve((size_t)G * 4);
  int*      krem    = (int*)carve((size_t)G * 4);
  int*      eqlist  = (int*)carve((size_t)G * CAP * 4);
  int*      bsum    = (int*)carve((size_t)16 * 4);
  int2*     csr2    = (int2*)carve((size_t)E * 8);        // compacted {src, w} at off[node]

  hipMemsetAsync(zbase, 0, zbytes, stream);

  // ---- deg (+ranks) + goff, then parallel scan ----
  k_deg_goff<<<512, 256, 0, stream>>>(dstv, batch, deg, goff, rank16);
  int nb = cdiv(N, 4096);   // 13
  k_scan_a<<<nb, 1024, 0, stream>>>(deg, off, bsum, N);
  k_scan_c<<<cdiv(N + 1, 256), 256, 0, stream>>>(off, bsum, N, nb);

  // ---- FUSED atomic-free fill + layer-1 gemm, 1:4 interleave ----
  k_fill_gemm<<<5 * NFB, dim3(64, 4), 0, stream>>>(srcv, dstv, rank16, batch, off,
                                                   csrp, einv,
                                                   x, W1l, W1r, b1l, yb, rb);

  // ---- layer-1 aggregation ----
  k_agg1<<<N / 8, dim3(64, 8), 0, stream>>>(yb, rb, csrp, off, h1);

  // ---- FUSED edge scores + layer-2 gemm2h (2:1 interleave), then radix top-k ----
  k_score_g2h<<<SB + GB2, dim3(64, 8), 0, stream>>>(h1, csrp, scoreu_csr, seg_csr, hist,
                                                    W2l, W2r, b2l, ybh, rb);
  k_scan<<<G, 64, 0, stream>>>(hist, prefix, krem, 0);
  for (int p = 1; p <= 2; ++p) {
    k_hist<<<cdiv(E / 4, 256), 256, 0, stream>>>(scoreu_csr, seg_csr, prefix, hist, p);
    k_scan<<<G, 64, 0, stream>>>(hist, prefix, krem, p);
  }
  k_select<<<cdiv(E / 4, 256), 256, 0, stream>>>(scoreu_csr, seg_csr, prefix,
                                                 eqcnt, eqlist, sel_csr);
  k_resolve<<<cdiv(G, 256), 256, 0, stream>>>(krem, eqcnt, eqlist, csrp, scoreu_csr,
                                              sel_csr);

  // ---- FUSED compact (weights from scoreu) + sampled back-permute ----
  k_samp_comp<<<N / 8 + cdiv(E / 4, 512), dim3(64, 8), 0, stream>>>(
      sel_csr, csrp, scoreu_csr, off, csr2, cnt2, einv, out_samp);

  // ---- layer 2 aggregation (projections already done inside score launch) ----
  k_agg_w<<<N / 8, dim3(64, 8), 0, stream>>>(ybh, rb, csr2, cnt2, off, h2);

  // ---- layer 3 ----
  k_gemm2h<H><<<N / 16, dim3(64, 4), 0, stream>>>(h2, W3l, W3r, b3l, ybh, rb);
  k_agg_w<<<N / 8, dim3(64, 8), 0, stream>>>(ybh, rb, csr2, cnt2, off, h3);

  // ---- fused pool + head ----
  k_poolhead<<<G, 512, 0, stream>>>(h3, goff, Wlin1, blin1, Wlin2, blin2, out_ls);
}